// Round 5
// baseline (1115.689 us; speedup 1.0000x reference)
//
#include <hip/hip_runtime.h>

typedef unsigned short u16;
typedef unsigned int   u32;
typedef __bf16 bf16x8 __attribute__((ext_vector_type(8)));
typedef u16    u16x8  __attribute__((ext_vector_type(8)));
typedef float  f32x4  __attribute__((ext_vector_type(4)));

#define DI static __device__ __forceinline__

DI float b2f(u16 u){ union { u32 i; float f; } c; c.i = ((u32)u) << 16; return c.f; }
DI u16 f2b(float f){ union { float f; u32 i; } c; c.f = f; u32 i = c.i;
                     return (u16)((i + 0x7FFFu + ((i >> 16) & 1u)) >> 16); }
DI float eluf(float x){ return x > 0.f ? x : (__expf(x) - 1.f); }
DI float sigf(float x){ return 1.f / (1.f + __expf(-x)); }
DI f32x4 mfma16(bf16x8 a, bf16x8 b, f32x4 c){
  return __builtin_amdgcn_mfma_f32_16x16x32_bf16(a, b, c, 0, 0, 0);
}
DI bf16x8 cvt8f(float4 a, float4 b){
  u16x8 t;
  t[0]=f2b(a.x); t[1]=f2b(a.y); t[2]=f2b(a.z); t[3]=f2b(a.w);
  t[4]=f2b(b.x); t[5]=f2b(b.y); t[6]=f2b(b.z); t[7]=f2b(b.w);
  return __builtin_bit_cast(bf16x8, t);
}
// prefetch 4x16B chunks of a [*, stride] tile column-slice into regs
DI void stage4(uint4* pf, const u16* base, int stride, int nrow, int ccol){
  #pragma unroll
  for (int i = 0; i < 4; i++)
    pf[i] = *(const uint4*)&base[(size_t)(nrow + i * 64) * stride + ccol];
}
DI void commit4(u16* buf, int nrow, int ccol, const uint4* pf){
  #pragma unroll
  for (int i = 0; i < 4; i++)
    *(uint4*)&buf[(nrow + i * 64) * 40 + ccol] = pf[i];
}
DI void mfma8(f32x4* acc, bf16x8 a, const u16* buf, int colbase, int ln, int q){
  #pragma unroll
  for (int nb = 0; nb < 8; nb++){
    bf16x8 b = *(const bf16x8*)&buf[(colbase + nb * 16 + ln) * 40 + q * 8];
    acc[nb] = mfma16(a, b, acc[nb]);
  }
}

// ---------------------------------------------------------------------------
// Transpose + fp32->bf16 convert weights into [N][K] (k-contiguous) in ws.
// ---------------------------------------------------------------------------
__global__ __launch_bounds__(256) void k_transpose(
    const float* __restrict__ vfc1, const float* __restrict__ vfc2,
    const float* __restrict__ vgate, const float* __restrict__ vskip,
    const float* __restrict__ wfc1, const float* __restrict__ wskip,
    u16* __restrict__ fc1T, u16* __restrict__ fc2T,
    u16* __restrict__ gateT, u16* __restrict__ skipT,
    u16* __restrict__ W1T, u16* __restrict__ WsT)
{
  const int z = blockIdx.z;
  const float* src; u16* dst; int K, N;
  if (z < 16)      { src = vfc1 + (size_t)z * 16384;       dst = fc1T + (size_t)z * 16384;       K = 64;   N = 256; }
  else if (z < 32) { src = vfc2 + (size_t)(z-16) * 65536;  dst = fc2T + (size_t)(z-16) * 65536;  K = 256;  N = 256; }
  else if (z < 48) { src = vgate + (size_t)(z-32) * 65536; dst = gateT + (size_t)(z-32) * 65536; K = 256;  N = 256; }
  else if (z < 64) { src = vskip + (size_t)(z-48) * 16384; dst = skipT + (size_t)(z-48) * 16384; K = 64;   N = 256; }
  else if (z == 64){ src = wfc1;  dst = W1T; K = 1024; N = 256; }
  else             { src = wskip; dst = WsT; K = 1024; N = 16;  }

  const int n0 = blockIdx.x * 32, k0 = blockIdx.y * 32;
  if (n0 >= N || k0 >= K) return;

  __shared__ u16 tile[32][33];
  const int tx = threadIdx.x, ty = threadIdx.y;
  #pragma unroll
  for (int i = 0; i < 4; i++){
    int k = k0 + ty + i * 8, n = n0 + tx;
    if (k < K && n < N) tile[ty + i * 8][tx] = f2b(src[(size_t)k * N + n]);
  }
  __syncthreads();
  #pragma unroll
  for (int i = 0; i < 4; i++){
    int n = n0 + ty + i * 8, k = k0 + tx;
    if (n < N && k < K) dst[(size_t)n * K + k] = tile[tx][ty + i * 8];
  }
}

// ---------------------------------------------------------------------------
// Kernel 1: weight GRN -> softmax weights w [N,16] (fp32, in ws)
// 512 blocks x 32 rows, 256 threads. Pipelined: prefetch tile r+1 during
// round r; 1 barrier/round; double LDS buffer. LDS 58.8 KB.
// ---------------------------------------------------------------------------
__global__ __launch_bounds__(256) void k_weight_grn(
    const float* __restrict__ x, const u16* __restrict__ W1T, const u16* __restrict__ WsT,
    const float* __restrict__ b1, const float* __restrict__ W2, const float* __restrict__ b2,
    const float* __restrict__ Wg, const float* __restrict__ bg, const float* __restrict__ bs,
    float* __restrict__ w_out)
{
  extern __shared__ char smem[];
  u16* sW0 = (u16*)smem;                    // [272][40]
  u16* sW1 = sW0 + 272 * 40;                // [272][40]
  u16* sH  = sW1 + 272 * 40;                // [32][260] bf16 h
  // post-K-loop overlays (sW0/sW1 regions are dead then):
  float* sW2f = (float*)smem;               // [256][16] fp32
  float* sWgf = sW2f + 4096;                // [16][16]
  float* sR   = (float*)(smem + 272 * 40 * 2); // [32][16]
  float* sY   = sR + 512;
  float* sG   = sY + 512;

  const int tid  = threadIdx.x;
  const int lane = tid & 63;
  const int wid  = tid >> 6;
  const int mb   = wid & 1;
  const int nh   = wid >> 1;
  const int ln   = lane & 15;
  const int q    = lane >> 4;
  const int row0 = blockIdx.x * 32;
  const int nb0  = nh ? 9 : 0;
  const int cnt  = nh ? 8 : 9;
  const int arow = mb * 16 + ln;
  const int grow = row0 + arow;
  const int nrow = tid >> 2;
  const int ccol = (tid & 3) * 8;

  f32x4 acc[9];
  #pragma unroll
  for (int i = 0; i < 9; i++){ acc[i][0]=0.f; acc[i][1]=0.f; acc[i][2]=0.f; acc[i][3]=0.f; }

  // prefetch round 0
  uint4 pf[4]; uint4 pf4 = {};
  stage4(pf, W1T, 1024, nrow, ccol);
  if (tid < 64) pf4 = *(const uint4*)&WsT[(size_t)(tid >> 2) * 1024 + ccol];
  float4 xc0 = *(const float4*)&x[(size_t)grow * 1024 + q * 8];
  float4 xc1 = *(const float4*)&x[(size_t)grow * 1024 + q * 8 + 4];

  for (int kt = 0; kt < 32; kt++){
    u16* cb = (kt & 1) ? sW1 : sW0;
    commit4(cb, nrow, ccol, pf);
    if (tid < 64) *(uint4*)&cb[(256 + (tid >> 2)) * 40 + ccol] = pf4;
    __syncthreads();
    const int kn = ((kt + 1) & 31) * 32;       // next round's k0 (wrap harmless)
    stage4(pf, W1T + kn, 1024, nrow, ccol);
    if (tid < 64) pf4 = *(const uint4*)&WsT[(size_t)(tid >> 2) * 1024 + kn + ccol];
    bf16x8 a = cvt8f(xc0, xc1);
    if (kt < 31){
      xc0 = *(const float4*)&x[(size_t)grow * 1024 + (kt + 1) * 32 + q * 8];
      xc1 = *(const float4*)&x[(size_t)grow * 1024 + (kt + 1) * 32 + q * 8 + 4];
    }
    #pragma unroll
    for (int i = 0; i < 9; i++){
      if (i < cnt){
        bf16x8 b = *(const bf16x8*)&cb[((nb0 + i) * 16 + ln) * 40 + q * 8];
        acc[i] = mfma16(a, b, acc[i]);
      }
    }
  }
  __syncthreads();   // all MFMA reads of sW0/sW1 done before overlay writes

  // epilogue: h -> sH (bf16), res -> sR (fp32); stage W2/Wg into LDS overlays
  #pragma unroll
  for (int i = 0; i < 9; i++){
    if (i < cnt){
      int col = (nb0 + i) * 16 + ln;
      float vb = (col < 256) ? b1[col] : bs[col - 256];
      #pragma unroll
      for (int r = 0; r < 4; r++){
        int lr = mb * 16 + q * 4 + r;
        float v = acc[i][r] + vb;
        if (col < 256) sH[lr * 260 + col] = f2b(eluf(v));
        else           sR[lr * 16 + (col - 256)] = v;
      }
    }
  }
  #pragma unroll
  for (int u = 0; u < 4; u++)
    *(float4*)&sW2f[tid * 16 + u * 4] = *(const float4*)&W2[tid * 16 + u * 4];
  sWgf[tid] = Wg[tid];
  __syncthreads();

  // y = h @ W2 + b2 : thread r = tid>>3 (0..31), 2 cols
  {
    int r = tid >> 3, j0 = (tid & 7) * 2;
    float a0 = b2[j0], a1 = b2[j0 + 1];
    #pragma unroll 8
    for (int k = 0; k < 256; k++){
      float h = b2f(sH[r * 260 + k]);
      a0 += h * sW2f[k * 16 + j0];
      a1 += h * sW2f[k * 16 + j0 + 1];
    }
    sY[r * 16 + j0] = a0; sY[r * 16 + j0 + 1] = a1;
  }
  __syncthreads();

  // gate = sigmoid(y @ Wg + bg)
  {
    int r = tid >> 3, j0 = (tid & 7) * 2;
    float g0 = bg[j0], g1 = bg[j0 + 1];
    #pragma unroll
    for (int k = 0; k < 16; k++){
      float yv = sY[r * 16 + k];
      g0 += yv * sWgf[k * 16 + j0];
      g1 += yv * sWgf[k * 16 + j0 + 1];
    }
    sG[r * 16 + j0] = sigf(g0); sG[r * 16 + j0 + 1] = sigf(g1);
  }
  __syncthreads();

  // softmax over 16
  if (tid < 32){
    int r = tid;
    float l[16]; float m = -1e30f;
    #pragma unroll
    for (int j = 0; j < 16; j++){
      float v = sR[r * 16 + j] + sG[r * 16 + j] * sY[r * 16 + j];
      l[j] = v; m = fmaxf(m, v);
    }
    float s = 0.f;
    #pragma unroll
    for (int j = 0; j < 16; j++){ l[j] = __expf(l[j] - m); s += l[j]; }
    float inv = 1.f / s;
    #pragma unroll
    for (int j = 0; j < 16; j++) w_out[(size_t)(row0 + r) * 16 + j] = l[j] * inv;
  }
}

// ---------------------------------------------------------------------------
// Kernel 2: per-variable GRNs, fully fused, pipelined (1 barrier/round,
// double-buffered sW, prefetch 1 round ahead). 512 blocks x 32 rows,
// 256 threads (4 waves: mb=wid&1 rows, nh=wid>>1 col-half). LDS 58.5 KB.
// ---------------------------------------------------------------------------
__global__ __launch_bounds__(256) void k_var_grn(
    const float* __restrict__ x,
    const u16* __restrict__ fc1T, const u16* __restrict__ fc2T,
    const u16* __restrict__ gateT, const u16* __restrict__ skipT,
    const float* __restrict__ b1, const float* __restrict__ b2,
    const float* __restrict__ bg, const float* __restrict__ bs,
    const float* __restrict__ w_in, float* __restrict__ out)
{
  extern __shared__ char smem[];
  u16* sW0 = (u16*)smem;               // [256][40]
  u16* sW1 = sW0 + 256 * 40;           // [256][40]
  u16* sH  = sW1 + 256 * 40;           // [32][264] bf16 hv then yv
  float* sWt = (float*)(sH + 32 * 264);// [32][16]  softmax weights fp32

  const int tid  = threadIdx.x;
  const int lane = tid & 63;
  const int wid  = tid >> 6;
  const int mb   = wid & 1;
  const int nh   = wid >> 1;
  const int ln   = lane & 15;
  const int q    = lane >> 4;
  const int row0 = blockIdx.x * 32;
  const int colbase = nh * 128;
  const int arow = mb * 16 + ln;
  const int grow = row0 + arow;
  const int nrow = tid >> 2;
  const int ccol = (tid & 3) * 8;

  #pragma unroll
  for (int i = 0; i < 2; i++){
    int idx = tid + i * 256;
    sWt[idx] = w_in[(size_t)(row0 + (idx >> 4)) * 16 + (idx & 15)];
  }

  f32x4 z[8];
  #pragma unroll
  for (int i = 0; i < 8; i++){ z[i][0]=0.f; z[i][1]=0.f; z[i][2]=0.f; z[i][3]=0.f; }

  const float* xrow = &x[(size_t)grow * 1024];
  float4 xf0 = *(const float4*)&xrow[q * 8];
  float4 xf1 = *(const float4*)&xrow[q * 8 + 4];
  float4 xf2 = *(const float4*)&xrow[32 + q * 8];
  float4 xf3 = *(const float4*)&xrow[32 + q * 8 + 4];

  uint4 pf[4];
  stage4(pf, fc1T, 64, nrow, ccol);   // round 0 tile (v=0, fc1, kr=0)

  for (int v = 0; v < 16; v++){
    const u16* fc1v  = fc1T  + (size_t)v * 16384;
    const u16* skipv = skipT + (size_t)v * 16384;
    const u16* fc2v  = fc2T  + (size_t)v * 65536;
    const u16* gatev = gateT + (size_t)v * 65536;
    const u16* fc1n  = fc1T  + (size_t)((v + 1) & 15) * 16384;

    bf16x8 a0 = cvt8f(xf0, xf1);
    bf16x8 a1 = cvt8f(xf2, xf3);

    // ---- phase 1a: hv = elu(Xv @ W1v + b1)
    f32x4 hacc[8];
    #pragma unroll
    for (int i = 0; i < 8; i++){ hacc[i][0]=0.f; hacc[i][1]=0.f; hacc[i][2]=0.f; hacc[i][3]=0.f; }
    commit4(sW0, nrow, ccol, pf); __syncthreads();
    stage4(pf, fc1v + 32, 64, nrow, ccol);
    mfma8(hacc, a0, sW0, colbase, ln, q);

    commit4(sW1, nrow, ccol, pf); __syncthreads();
    stage4(pf, skipv, 64, nrow, ccol);
    mfma8(hacc, a1, sW1, colbase, ln, q);

    #pragma unroll
    for (int nb = 0; nb < 8; nb++){
      int col = colbase + nb * 16 + ln;
      float vb = b1[v * 256 + col];
      #pragma unroll
      for (int r = 0; r < 4; r++)
        sH[(mb * 16 + q * 4 + r) * 264 + col] = f2b(eluf(hacc[nb][r] + vb));
    }

    // ---- phase 1b: rv = Xv @ Wsv + bs ; z += wv * rv
    f32x4 racc[8];
    #pragma unroll
    for (int i = 0; i < 8; i++){ racc[i][0]=0.f; racc[i][1]=0.f; racc[i][2]=0.f; racc[i][3]=0.f; }
    commit4(sW0, nrow, ccol, pf); __syncthreads();
    stage4(pf, skipv + 32, 64, nrow, ccol);
    mfma8(racc, a0, sW0, colbase, ln, q);

    commit4(sW1, nrow, ccol, pf); __syncthreads();
    stage4(pf, fc2v, 256, nrow, ccol);
    mfma8(racc, a1, sW1, colbase, ln, q);

    float wv[4];
    #pragma unroll
    for (int r = 0; r < 4; r++) wv[r] = sWt[(mb * 16 + q * 4 + r) * 16 + v];
    #pragma unroll
    for (int nb = 0; nb < 8; nb++){
      int col = colbase + nb * 16 + ln;
      float vb = bs[v * 256 + col];
      #pragma unroll
      for (int r = 0; r < 4; r++) z[nb][r] += wv[r] * (racc[nb][r] + vb);
    }

    // ---- phase 2: yv = hv @ W2v + b2 (8 rounds of K=32)
    f32x4 yacc[8];
    #pragma unroll
    for (int i = 0; i < 8; i++){ yacc[i][0]=0.f; yacc[i][1]=0.f; yacc[i][2]=0.f; yacc[i][3]=0.f; }
    #pragma unroll
    for (int kc = 0; kc < 8; kc++){
      u16* cb = (kc & 1) ? sW1 : sW0;
      commit4(cb, nrow, ccol, pf); __syncthreads();
      if (kc == 3){  // refresh x prefetch for next v (plenty of cover left)
        const float* xr = &x[(size_t)grow * 1024 + ((v + 1) & 15) * 64];
        xf0 = *(const float4*)&xr[q * 8];
        xf1 = *(const float4*)&xr[q * 8 + 4];
        xf2 = *(const float4*)&xr[32 + q * 8];
        xf3 = *(const float4*)&xr[32 + q * 8 + 4];
      }
      if (kc < 7) stage4(pf, fc2v + (kc + 1) * 32, 256, nrow, ccol);
      else        stage4(pf, gatev, 256, nrow, ccol);
      bf16x8 ah = *(const bf16x8*)&sH[arow * 264 + kc * 32 + q * 8];
      mfma8(yacc, ah, cb, colbase, ln, q);
    }
    __syncthreads();   // protect sH overwrite vs other waves' kc=7 reads

    f32x4 ysave[8];
    #pragma unroll
    for (int nb = 0; nb < 8; nb++){
      int col = colbase + nb * 16 + ln;
      float vb = b2[v * 256 + col];
      #pragma unroll
      for (int r = 0; r < 4; r++){
        float yy = yacc[nb][r] + vb;
        ysave[nb][r] = yy;
        sH[(mb * 16 + q * 4 + r) * 264 + col] = f2b(yy);
      }
    }

    // ---- phase 3: gv = sigmoid(yv @ Wgv + bg) (8 rounds of K=32)
    f32x4 gacc[8];
    #pragma unroll
    for (int i = 0; i < 8; i++){ gacc[i][0]=0.f; gacc[i][1]=0.f; gacc[i][2]=0.f; gacc[i][3]=0.f; }
    #pragma unroll
    for (int kc = 0; kc < 8; kc++){
      u16* cb = (kc & 1) ? sW1 : sW0;
      commit4(cb, nrow, ccol, pf); __syncthreads();
      if (kc < 7) stage4(pf, gatev + (kc + 1) * 32, 256, nrow, ccol);
      else        stage4(pf, fc1n, 64, nrow, ccol);
      bf16x8 ah = *(const bf16x8*)&sH[arow * 264 + kc * 32 + q * 8];
      mfma8(gacc, ah, cb, colbase, ln, q);
    }

    #pragma unroll
    for (int nb = 0; nb < 8; nb++){
      int col = colbase + nb * 16 + ln;
      float vb = bg[v * 256 + col];
      #pragma unroll
      for (int r = 0; r < 4; r++)
        z[nb][r] += wv[r] * sigf(gacc[nb][r] + vb) * ysave[nb][r];
    }
  }

  // store z -> out (fp32), C/D layout: row = q*4+reg, col = lane&15
  #pragma unroll
  for (int nb = 0; nb < 8; nb++){
    int col = colbase + nb * 16 + ln;
    #pragma unroll
    for (int r = 0; r < 4; r++){
      int row = row0 + mb * 16 + q * 4 + r;
      out[(size_t)row * 256 + col] = z[nb][r];
    }
  }
}

// ---------------------------------------------------------------------------
extern "C" void kernel_launch(void* const* d_in, const int* in_sizes, int n_in,
                              void* d_out, int out_size, void* d_ws, size_t ws_size,
                              hipStream_t stream)
{
  const float* x     = (const float*)d_in[0];
  const float* wfc1w = (const float*)d_in[1];
  const float* wfc1b = (const float*)d_in[2];
  const float* wfc2w = (const float*)d_in[3];
  const float* wfc2b = (const float*)d_in[4];
  const float* wgw   = (const float*)d_in[5];
  const float* wgb   = (const float*)d_in[6];
  const float* wsw   = (const float*)d_in[7];
  const float* wsb   = (const float*)d_in[8];
  const float* vfc1w = (const float*)d_in[9];
  const float* vfc1b = (const float*)d_in[10];
  const float* vfc2w = (const float*)d_in[11];
  const float* vfc2b = (const float*)d_in[12];
  const float* vgw   = (const float*)d_in[13];
  const float* vgb   = (const float*)d_in[14];
  const float* vsw   = (const float*)d_in[15];
  const float* vsb   = (const float*)d_in[16];

  u16* ws    = (u16*)d_ws;
  u16* fc1T  = ws;                     // 16*256*64   = 262144 elems (bf16)
  u16* fc2T  = fc1T + 262144;          // 1048576
  u16* gateT = fc2T + 1048576;         // 1048576
  u16* skipT = gateT + 1048576;        // 262144
  u16* W1T   = skipT + 262144;         // 262144
  u16* WsT   = W1T + 262144;           // 16384
  float* w_ws = (float*)(WsT + 16384); // 16384*16 fp32

  k_transpose<<<dim3(8, 32, 66), dim3(32, 8, 1), 0, stream>>>(
      vfc1w, vfc2w, vgw, vsw, wfc1w, wsw, fc1T, fc2T, gateT, skipT, W1T, WsT);

  size_t sm1 = (size_t)(272 * 40 * 2 + 32 * 260) * 2; // 60160 B
  k_weight_grn<<<dim3(512), dim3(256), sm1, stream>>>(
      x, W1T, WsT, wfc1b, wfc2w, wfc2b, wgw, wgb, wsb, w_ws);

  size_t sm2 = (size_t)(256 * 40 * 2 + 32 * 264) * 2 + (size_t)(32 * 16) * 4; // 59904 B
  k_var_grn<<<dim3(512), dim3(256), sm2, stream>>>(
      x, fc1T, fc2T, gateT, skipT, vfc1b, vfc2b, vgb, vsb, w_ws, (float*)d_out);
}

// Round 6
// 473.202 us; speedup vs baseline: 2.3577x; 2.3577x over previous
//
#include <hip/hip_runtime.h>

typedef unsigned short u16;
typedef unsigned int   u32;
typedef __bf16 bf16x8 __attribute__((ext_vector_type(8)));
typedef u16    u16x8  __attribute__((ext_vector_type(8)));
typedef float  f32x4  __attribute__((ext_vector_type(4)));

#define DI static __device__ __forceinline__

DI float b2f(u16 u){ union { u32 i; float f; } c; c.i = ((u32)u) << 16; return c.f; }
DI u16 f2b(float f){ union { float f; u32 i; } c; c.f = f; u32 i = c.i;
                     return (u16)((i + 0x7FFFu + ((i >> 16) & 1u)) >> 16); }
DI float eluf(float x){ return x > 0.f ? x : (__expf(x) - 1.f); }
DI float sigf(float x){ return 1.f / (1.f + __expf(-x)); }
DI f32x4 mfma16(bf16x8 a, bf16x8 b, f32x4 c){
  return __builtin_amdgcn_mfma_f32_16x16x32_bf16(a, b, c, 0, 0, 0);
}
DI bf16x8 cvt8f(float4 a, float4 b){
  u16x8 t;
  t[0]=f2b(a.x); t[1]=f2b(a.y); t[2]=f2b(a.z); t[3]=f2b(a.w);
  t[4]=f2b(b.x); t[5]=f2b(b.y); t[6]=f2b(b.z); t[7]=f2b(b.w);
  return __builtin_bit_cast(bf16x8, t);
}
DI bf16x8 ldb(const u16* p){ return *(const bf16x8*)p; }

// ---------------------------------------------------------------------------
// Pack all weights (fp32 -> bf16) into MFMA B-fragment order:
//   frag[tile][kc][lane(64)][8], element = W[k = kc*32 + (lane>>4)*8 + j]
//                                          [n = nb*16 + (lane&15)]
// so a wave's B-load for (nb,kc) is one fully-coalesced 1 KB read.
// Ranges (8-elem groups): pW1 34816 | pF1 32768 | pSk 32768 | pF2 131072 | pGa 131072
// ---------------------------------------------------------------------------
__global__ __launch_bounds__(256) void k_pack(
    const float* __restrict__ wfc1, const float* __restrict__ wskip,
    const float* __restrict__ vfc1, const float* __restrict__ vfc2,
    const float* __restrict__ vgate, const float* __restrict__ vskip,
    u16* __restrict__ pW1, u16* __restrict__ pF1, u16* __restrict__ pSk,
    u16* __restrict__ pF2, u16* __restrict__ pGa)
{
  const int g = blockIdx.x * 256 + threadIdx.x;   // 362496 total
  float v8[8];
  u16* dst;
  if (g < 34816){                 // pW1: nb 0..16, kc 0..31 (K=1024)
    int idx = g, lane = idx & 63, kc = (idx >> 6) & 31, nb = idx >> 11;
    int ln = lane & 15, q = lane >> 4;
    #pragma unroll
    for (int j = 0; j < 8; j++){
      int k = kc * 32 + q * 8 + j;
      v8[j] = (nb < 16) ? wfc1[(size_t)k * 256 + nb * 16 + ln]
                        : wskip[(size_t)k * 16 + ln];
    }
    dst = pW1 + (size_t)idx * 8;
  } else if (g < 67584){          // pF1: v, nb 0..15, kc 0..1 (K=64)
    int idx = g - 34816, lane = idx & 63, kc = (idx >> 6) & 1, nb = (idx >> 7) & 15, v = idx >> 11;
    int ln = lane & 15, q = lane >> 4;
    #pragma unroll
    for (int j = 0; j < 8; j++){
      int k = kc * 32 + q * 8 + j;
      v8[j] = vfc1[((size_t)v * 64 + k) * 256 + nb * 16 + ln];
    }
    dst = pF1 + (size_t)idx * 8;
  } else if (g < 100352){         // pSk
    int idx = g - 67584, lane = idx & 63, kc = (idx >> 6) & 1, nb = (idx >> 7) & 15, v = idx >> 11;
    int ln = lane & 15, q = lane >> 4;
    #pragma unroll
    for (int j = 0; j < 8; j++){
      int k = kc * 32 + q * 8 + j;
      v8[j] = vskip[((size_t)v * 64 + k) * 256 + nb * 16 + ln];
    }
    dst = pSk + (size_t)idx * 8;
  } else if (g < 231424){         // pF2: v, nb, kc 0..7 (K=256)
    int idx = g - 100352, lane = idx & 63, kc = (idx >> 6) & 7, nb = (idx >> 9) & 15, v = idx >> 13;
    int ln = lane & 15, q = lane >> 4;
    #pragma unroll
    for (int j = 0; j < 8; j++){
      int k = kc * 32 + q * 8 + j;
      v8[j] = vfc2[((size_t)v * 256 + k) * 256 + nb * 16 + ln];
    }
    dst = pF2 + (size_t)idx * 8;
  } else {                        // pGa
    int idx = g - 231424, lane = idx & 63, kc = (idx >> 6) & 7, nb = (idx >> 9) & 15, v = idx >> 13;
    int ln = lane & 15, q = lane >> 4;
    #pragma unroll
    for (int j = 0; j < 8; j++){
      int k = kc * 32 + q * 8 + j;
      v8[j] = vgate[((size_t)v * 256 + k) * 256 + nb * 16 + ln];
    }
    dst = pGa + (size_t)idx * 8;
  }
  u16x8 t;
  #pragma unroll
  for (int j = 0; j < 8; j++) t[j] = f2b(v8[j]);
  *(uint4*)dst = __builtin_bit_cast(uint4, t);
}

// ---------------------------------------------------------------------------
// Kernel 1: weight GRN -> softmax weights w [N,16] (fp32, in ws)
// 256 blocks x 64 rows, 512 threads = 8 waves. Wave wid owns col-slice:
// waves 0..6 -> nb {2w, 2w+1}; wave 7 -> nb {14, 15, 16(=skip cols)}.
// B-fragments streamed directly from global packed pW1 (no LDS, no barriers
// in the K-loop). Epilogue (y/gate/softmax) uses LDS.
// ---------------------------------------------------------------------------
__global__ __launch_bounds__(512) void k_weight_grn(
    const float* __restrict__ x, const u16* __restrict__ pW1,
    const float* __restrict__ b1, const float* __restrict__ W2, const float* __restrict__ b2,
    const float* __restrict__ Wg, const float* __restrict__ bg, const float* __restrict__ bs,
    float* __restrict__ w_out)
{
  __shared__ u16 sH[64 * 264];       // bf16 h
  __shared__ float sR[64 * 16];      // res fp32
  __shared__ float sY[64 * 16];
  __shared__ float sG[64 * 16];
  __shared__ float sW2f[256 * 16];   // fp32 W2
  __shared__ float sWgf[256];        // fp32 Wg

  const int tid  = threadIdx.x;
  const int lane = tid & 63;
  const int wid  = tid >> 6;
  const int ln   = lane & 15;
  const int q    = lane >> 4;
  const int row0 = blockIdx.x * 64;
  const int nb0  = wid * 2;
  const int ncnt = (wid == 7) ? 3 : 2;

  f32x4 acc[4][3];
  #pragma unroll
  for (int mb = 0; mb < 4; mb++)
    #pragma unroll
    for (int i = 0; i < 3; i++){ acc[mb][i][0]=0.f; acc[mb][i][1]=0.f; acc[mb][i][2]=0.f; acc[mb][i][3]=0.f; }

  for (int kc = 0; kc < 32; kc++){
    bf16x8 a[4];
    #pragma unroll
    for (int mb = 0; mb < 4; mb++){
      const float* xp = &x[(size_t)(row0 + mb * 16 + ln) * 1024 + kc * 32 + q * 8];
      a[mb] = cvt8f(*(const float4*)xp, *(const float4*)(xp + 4));
    }
    #pragma unroll
    for (int i = 0; i < 3; i++){
      if (i < ncnt){
        bf16x8 b = ldb(&pW1[(size_t)((nb0 + i) * 32 + kc) * 512 + lane * 8]);
        #pragma unroll
        for (int mb = 0; mb < 4; mb++) acc[mb][i] = mfma16(a[mb], b, acc[mb][i]);
      }
    }
  }

  // write h (bf16) / res (fp32)
  #pragma unroll
  for (int i = 0; i < 3; i++){
    if (i < ncnt){
      int nb = nb0 + i;
      int col = nb * 16 + ln;
      float vb = (nb < 16) ? b1[col] : bs[ln];
      #pragma unroll
      for (int mb = 0; mb < 4; mb++){
        #pragma unroll
        for (int r = 0; r < 4; r++){
          int lr = mb * 16 + q * 4 + r;
          float v = acc[mb][i][r] + vb;
          if (nb < 16) sH[lr * 264 + col] = f2b(eluf(v));
          else         sR[lr * 16 + ln] = v;
        }
      }
    }
  }
  // stage W2 [256][16] fp32 + Wg
  #pragma unroll
  for (int u = 0; u < 2; u++)
    *(float4*)&sW2f[tid * 8 + u * 4] = *(const float4*)&W2[tid * 8 + u * 4];
  if (tid < 256) sWgf[tid] = Wg[tid];
  __syncthreads();

  // y = h @ W2 + b2 : thread r = tid>>3 (0..63), 2 cols
  {
    int r = tid >> 3, j0 = (tid & 7) * 2;
    float a0 = b2[j0], a1 = b2[j0 + 1];
    #pragma unroll 8
    for (int k = 0; k < 256; k++){
      float h = b2f(sH[r * 264 + k]);
      a0 += h * sW2f[k * 16 + j0];
      a1 += h * sW2f[k * 16 + j0 + 1];
    }
    sY[r * 16 + j0] = a0; sY[r * 16 + j0 + 1] = a1;
  }
  __syncthreads();

  // gate = sigmoid(y @ Wg + bg)
  {
    int r = tid >> 3, j0 = (tid & 7) * 2;
    float g0 = bg[j0], g1 = bg[j0 + 1];
    #pragma unroll
    for (int k = 0; k < 16; k++){
      float yv = sY[r * 16 + k];
      g0 += yv * sWgf[k * 16 + j0];
      g1 += yv * sWgf[k * 16 + j0 + 1];
    }
    sG[r * 16 + j0] = sigf(g0); sG[r * 16 + j0 + 1] = sigf(g1);
  }
  __syncthreads();

  // softmax over 16
  if (tid < 64){
    int r = tid;
    float l[16]; float m = -1e30f;
    #pragma unroll
    for (int j = 0; j < 16; j++){
      float v = sR[r * 16 + j] + sG[r * 16 + j] * sY[r * 16 + j];
      l[j] = v; m = fmaxf(m, v);
    }
    float s = 0.f;
    #pragma unroll
    for (int j = 0; j < 16; j++){ l[j] = __expf(l[j] - m); s += l[j]; }
    float inv = 1.f / s;
    #pragma unroll
    for (int j = 0; j < 16; j++) w_out[(size_t)(row0 + r) * 16 + j] = l[j] * inv;
  }
}

// ---------------------------------------------------------------------------
// Kernel 2: per-variable GRNs, fully fused. 256 blocks x 64 rows, 512 threads
// = 8 waves; wave wid owns 32-col slice (nb {2w, 2w+1}) for ALL 64 rows
// (mb 0..3). Weights streamed directly from packed global fragments (no LDS
// staging). Only hv/yv round-trip through LDS: 4 barriers per v.
// ---------------------------------------------------------------------------
__global__ __launch_bounds__(512) void k_var_grn(
    const float* __restrict__ x,
    const u16* __restrict__ pF1, const u16* __restrict__ pSk,
    const u16* __restrict__ pF2, const u16* __restrict__ pGa,
    const float* __restrict__ b1, const float* __restrict__ b2,
    const float* __restrict__ bg, const float* __restrict__ bs,
    const float* __restrict__ w_in, float* __restrict__ out)
{
  __shared__ u16 sH[64 * 264];       // bf16 hv then yv
  __shared__ float sWt[64 * 16];     // softmax weights fp32

  const int tid  = threadIdx.x;
  const int lane = tid & 63;
  const int wid  = tid >> 6;
  const int ln   = lane & 15;
  const int q    = lane >> 4;
  const int row0 = blockIdx.x * 64;
  const int nb0  = wid * 2;

  sWt[tid]       = w_in[(size_t)row0 * 16 + tid];
  sWt[tid + 512] = w_in[(size_t)row0 * 16 + 512 + tid];
  __syncthreads();

  float wv[4][4];                    // [mb][r]
  #pragma unroll
  for (int mb = 0; mb < 4; mb++)
    #pragma unroll
    for (int r = 0; r < 4; r++) wv[mb][r] = 0.f;   // loaded per v below

  f32x4 z[4][2];
  #pragma unroll
  for (int mb = 0; mb < 4; mb++)
    #pragma unroll
    for (int i = 0; i < 2; i++){ z[mb][i][0]=0.f; z[mb][i][1]=0.f; z[mb][i][2]=0.f; z[mb][i][3]=0.f; }

  for (int v = 0; v < 16; v++){
    // A-fragments from x (fp32 -> bf16), ks=0/1 halves of K=64
    bf16x8 a0[4], a1[4];
    #pragma unroll
    for (int mb = 0; mb < 4; mb++){
      const float* xp = &x[(size_t)(row0 + mb * 16 + ln) * 1024 + v * 64 + q * 8];
      a0[mb] = cvt8f(*(const float4*)xp, *(const float4*)(xp + 4));
      a1[mb] = cvt8f(*(const float4*)(xp + 32), *(const float4*)(xp + 36));
    }
    #pragma unroll
    for (int mb = 0; mb < 4; mb++)
      #pragma unroll
      for (int r = 0; r < 4; r++) wv[mb][r] = sWt[(mb * 16 + q * 4 + r) * 16 + v];

    // ---- phase 1a: hv = elu(Xv @ W1v + b1)
    f32x4 hacc[4][2];
    #pragma unroll
    for (int mb = 0; mb < 4; mb++)
      #pragma unroll
      for (int i = 0; i < 2; i++){ hacc[mb][i][0]=0.f; hacc[mb][i][1]=0.f; hacc[mb][i][2]=0.f; hacc[mb][i][3]=0.f; }
    #pragma unroll
    for (int ks = 0; ks < 2; ks++){
      bf16x8 B0 = ldb(&pF1[(size_t)((v * 16 + nb0) * 2 + ks) * 512 + lane * 8]);
      bf16x8 B1 = ldb(&pF1[(size_t)((v * 16 + nb0 + 1) * 2 + ks) * 512 + lane * 8]);
      #pragma unroll
      for (int mb = 0; mb < 4; mb++){
        bf16x8 a = ks ? a1[mb] : a0[mb];
        hacc[mb][0] = mfma16(a, B0, hacc[mb][0]);
        hacc[mb][1] = mfma16(a, B1, hacc[mb][1]);
      }
    }
    #pragma unroll
    for (int i = 0; i < 2; i++){
      int col = (nb0 + i) * 16 + ln;
      float vb = b1[v * 256 + col];
      #pragma unroll
      for (int mb = 0; mb < 4; mb++)
        #pragma unroll
        for (int r = 0; r < 4; r++)
          sH[(mb * 16 + q * 4 + r) * 264 + col] = f2b(eluf(hacc[mb][i][r] + vb));
    }

    // ---- phase 1b: rv = Xv @ Wsv + bs ; z += wv * rv  (no sH dependency)
    f32x4 racc[4][2];
    #pragma unroll
    for (int mb = 0; mb < 4; mb++)
      #pragma unroll
      for (int i = 0; i < 2; i++){ racc[mb][i][0]=0.f; racc[mb][i][1]=0.f; racc[mb][i][2]=0.f; racc[mb][i][3]=0.f; }
    #pragma unroll
    for (int ks = 0; ks < 2; ks++){
      bf16x8 B0 = ldb(&pSk[(size_t)((v * 16 + nb0) * 2 + ks) * 512 + lane * 8]);
      bf16x8 B1 = ldb(&pSk[(size_t)((v * 16 + nb0 + 1) * 2 + ks) * 512 + lane * 8]);
      #pragma unroll
      for (int mb = 0; mb < 4; mb++){
        bf16x8 a = ks ? a1[mb] : a0[mb];
        racc[mb][0] = mfma16(a, B0, racc[mb][0]);
        racc[mb][1] = mfma16(a, B1, racc[mb][1]);
      }
    }
    #pragma unroll
    for (int i = 0; i < 2; i++){
      float vb = bs[v * 256 + (nb0 + i) * 16 + ln];
      #pragma unroll
      for (int mb = 0; mb < 4; mb++)
        #pragma unroll
        for (int r = 0; r < 4; r++) z[mb][i][r] += wv[mb][r] * (racc[mb][i][r] + vb);
    }
    __syncthreads();   // (1) hv visible to all waves

    // ---- phase 2: yv = hv @ W2v + b2  (K=256 streamed, no inner barriers)
    f32x4 yacc[4][2];
    #pragma unroll
    for (int mb = 0; mb < 4; mb++)
      #pragma unroll
      for (int i = 0; i < 2; i++){ yacc[mb][i][0]=0.f; yacc[mb][i][1]=0.f; yacc[mb][i][2]=0.f; yacc[mb][i][3]=0.f; }
    #pragma unroll
    for (int kc = 0; kc < 8; kc++){
      bf16x8 B0 = ldb(&pF2[(size_t)((v * 16 + nb0) * 8 + kc) * 512 + lane * 8]);
      bf16x8 B1 = ldb(&pF2[(size_t)((v * 16 + nb0 + 1) * 8 + kc) * 512 + lane * 8]);
      #pragma unroll
      for (int mb = 0; mb < 4; mb++){
        bf16x8 ah = *(const bf16x8*)&sH[(mb * 16 + ln) * 264 + kc * 32 + q * 8];
        yacc[mb][0] = mfma16(ah, B0, yacc[mb][0]);
        yacc[mb][1] = mfma16(ah, B1, yacc[mb][1]);
      }
    }
    __syncthreads();   // (2) all hv reads done before yv overwrite

    f32x4 ysave[4][2];
    #pragma unroll
    for (int i = 0; i < 2; i++){
      int col = (nb0 + i) * 16 + ln;
      float vb = b2[v * 256 + col];
      #pragma unroll
      for (int mb = 0; mb < 4; mb++)
        #pragma unroll
        for (int r = 0; r < 4; r++){
          float yy = yacc[mb][i][r] + vb;
          ysave[mb][i][r] = yy;
          sH[(mb * 16 + q * 4 + r) * 264 + col] = f2b(yy);
        }
    }
    __syncthreads();   // (3) yv visible

    // ---- phase 3: gv = sigmoid(yv @ Wgv + bg)
    f32x4 gacc[4][2];
    #pragma unroll
    for (int mb = 0; mb < 4; mb++)
      #pragma unroll
      for (int i = 0; i < 2; i++){ gacc[mb][i][0]=0.f; gacc[mb][i][1]=0.f; gacc[mb][i][2]=0.f; gacc[mb][i][3]=0.f; }
    #pragma unroll
    for (int kc = 0; kc < 8; kc++){
      bf16x8 B0 = ldb(&pGa[(size_t)((v * 16 + nb0) * 8 + kc) * 512 + lane * 8]);
      bf16x8 B1 = ldb(&pGa[(size_t)((v * 16 + nb0 + 1) * 8 + kc) * 512 + lane * 8]);
      #pragma unroll
      for (int mb = 0; mb < 4; mb++){
        bf16x8 ah = *(const bf16x8*)&sH[(mb * 16 + ln) * 264 + kc * 32 + q * 8];
        gacc[mb][0] = mfma16(ah, B0, gacc[mb][0]);
        gacc[mb][1] = mfma16(ah, B1, gacc[mb][1]);
      }
    }
    #pragma unroll
    for (int i = 0; i < 2; i++){
      float vb = bg[v * 256 + (nb0 + i) * 16 + ln];
      #pragma unroll
      for (int mb = 0; mb < 4; mb++)
        #pragma unroll
        for (int r = 0; r < 4; r++)
          z[mb][i][r] += wv[mb][r] * sigf(gacc[mb][i][r] + vb) * ysave[mb][i][r];
    }
    __syncthreads();   // (4) yv reads done before next v's hv writes
  }

  // store z -> out (fp32), C/D layout: row = q*4+reg, col = lane&15
  #pragma unroll
  for (int i = 0; i < 2; i++){
    int col = (nb0 + i) * 16 + ln;
    #pragma unroll
    for (int mb = 0; mb < 4; mb++)
      #pragma unroll
      for (int r = 0; r < 4; r++)
        out[(size_t)(row0 + mb * 16 + q * 4 + r) * 256 + col] = z[mb][i][r];
  }
}

// ---------------------------------------------------------------------------
extern "C" void kernel_launch(void* const* d_in, const int* in_sizes, int n_in,
                              void* d_out, int out_size, void* d_ws, size_t ws_size,
                              hipStream_t stream)
{
  const float* x     = (const float*)d_in[0];
  const float* wfc1w = (const float*)d_in[1];
  const float* wfc1b = (const float*)d_in[2];
  const float* wfc2w = (const float*)d_in[3];
  const float* wfc2b = (const float*)d_in[4];
  const float* wgw   = (const float*)d_in[5];
  const float* wgb   = (const float*)d_in[6];
  const float* wsw   = (const float*)d_in[7];
  const float* wsb   = (const float*)d_in[8];
  const float* vfc1w = (const float*)d_in[9];
  const float* vfc1b = (const float*)d_in[10];
  const float* vfc2w = (const float*)d_in[11];
  const float* vfc2b = (const float*)d_in[12];
  const float* vgw   = (const float*)d_in[13];
  const float* vgb   = (const float*)d_in[14];
  const float* vsw   = (const float*)d_in[15];
  const float* vsb   = (const float*)d_in[16];

  u16* ws   = (u16*)d_ws;
  u16* pW1  = ws;                      // 278528 u16
  u16* pF1  = pW1 + 278528;            // 262144
  u16* pSk  = pF1 + 262144;            // 262144
  u16* pF2  = pSk + 262144;            // 1048576
  u16* pGa  = pF2 + 1048576;           // 1048576
  float* w_ws = (float*)(pGa + 1048576); // 16384*16 fp32

  k_pack<<<dim3(1416), dim3(256), 0, stream>>>(
      wfc1w, wsw, vfc1w, vfc2w, vgw, vsw, pW1, pF1, pSk, pF2, pGa);

  k_weight_grn<<<dim3(256), dim3(512), 0, stream>>>(
      x, pW1, wfc1b, wfc2w, wfc2b, wgw, wgb, wsb, w_ws);

  k_var_grn<<<dim3(256), dim3(512), 0, stream>>>(
      x, pF1, pSk, pF2, pGa, vfc1b, vfc2b, vgb, vsb, w_ws, (float*)d_out);
}